// Round 1
// baseline (702.613 us; speedup 1.0000x reference)
//
#include <hip/hip_runtime.h>
#include <math.h>

#define EPSF 1e-5f
#define MAXNF (1.0f - 1e-5f)

constexpr int SEGc = 24;
constexpr int Nn   = 14;    // L / SEG
constexpr int Tt   = 4;     // horizons
constexpr int Bb   = 32;
constexpr int Ll   = 336;
constexpr int Ff   = 256;
constexpr int Dd   = 128;
constexpr int Hh   = 256;
constexpr int BFc  = Bb * Ff;   // 8192

__device__ __forceinline__ float wsum64(float v) {
#pragma unroll
    for (int off = 1; off < 64; off <<= 1) v += __shfl_xor(v, off, 64);
    return v;  // all lanes hold the total
}

// ---------------- Kernel 1: RevIN stats ----------------
__global__ __launch_bounds__(256) void stats_kernel(
    const float* __restrict__ tr, const float* __restrict__ sc,
    const float* __restrict__ sf, const float* __restrict__ re,
    float* __restrict__ ws)
{
    const int b = blockIdx.x;
    const int f = threadIdx.x;
    const int base = b * Ll * Ff + f;
    float sum = 0.f, sumsq = 0.f;
    for (int l = 0; l < Ll; ++l) {
        const int idx = base + l * Ff;
        float x = tr[idx] + sc[idx] + sf[idx] + re[idx];
        sum += x; sumsq += x * x;
    }
    const float mean = sum / (float)Ll;
    const float var  = sumsq / (float)Ll - mean * mean;
    ws[b * Ff + f]        = mean;
    ws[BFc + b * Ff + f]  = sqrtf(var + 1e-5f);
}

// ---------------- Kernel 2: full pipeline, one wave per bf ----------------
__global__ __launch_bounds__(64) void branch_kernel(
    const float* __restrict__ trend, const float* __restrict__ scoarse,
    const float* __restrict__ sfine, const float* __restrict__ resid,
    const float* __restrict__ revin_w, const float* __restrict__ revin_b,
    const float* __restrict__ enc_W, const float* __restrict__ enc_b,
    const float* __restrict__ vel_W, const float* __restrict__ vel_b,
    const float* __restrict__ steps, const float* __restrict__ mobius_w,
    const float* __restrict__ rec_W1, const float* __restrict__ rec_b1,
    const float* __restrict__ rec_W2, const float* __restrict__ rec_b2,
    const float* __restrict__ ws_stats, float* __restrict__ out,
    float* __restrict__ hpart)
{
    const int bf   = blockIdx.x;
    const int b    = bf >> 8;
    const int f    = bf & 255;
    const int lane = threadIdx.x;
    const int d0 = lane, d1 = lane + 64;

    __shared__ float xs[Nn * SEGc];       // one component's collapsed rows
    __shared__ float bc[Dd];              // broadcast buffer for matmuls
    __shared__ float zfl[4][Tt][Dd];      // z_fut for all comps
    __shared__ float zfns[4][Tt];         // clipped norms of z_fut
    __shared__ float uls[Tt][Dd];         // logmap0(comb) per horizon
    __shared__ float hbuf[Tt][Hh];        // hidden layer

    const float mean    = ws_stats[bf];
    const float stdv    = ws_stats[BFc + bf];
    const float inv_std = 1.f / stdv;
    const float rw = revin_w[f], rb = revin_b[f];

    // v_init weights: w_j = 0.9^(12-j); coeff = w_j / (sum(w) * 13)
    float Wsum = 0.f;
    for (int j = 0; j < Nn - 1; ++j) Wsum += powf(0.9f, (float)(Nn - 2 - j));
    const float wnorm = 1.f / (Wsum * (float)(Nn - 1));

    for (int c = 0; c < 4; ++c) {
        const float* cp = (c == 0) ? trend : (c == 1) ? scoarse : (c == 2) ? sfine : resid;
        __syncthreads();
        for (int i = lane; i < Nn * SEGc; i += 64) {
            float raw = cp[(b * Ll + i) * Ff + f];
            xs[i] = ((raw - 0.25f * mean) * inv_std) * rw + 0.25f * rb;
        }
        __syncthreads();

        const float* We = enc_W + c * SEGc * Dd;
        const float* Wv = vel_W + c * Dd * Dd;
        const float be0 = enc_b[c * Dd + d0], be1 = enc_b[c * Dd + d1];
        const float bv0 = vel_b[c * Dd + d0], bv1 = vel_b[c * Dd + d1];

        float vi0 = 0.f, vi1 = 0.f;
        float zp0 = 0.f, zp1 = 0.f, zpn2 = 0.f;
        float z0 = 0.f, z1 = 0.f, zn2 = 0.f;
        for (int n = 0; n < Nn; ++n) {
            float y0 = be0, y1 = be1;
            for (int s = 0; s < SEGc; ++s) {
                const float xv = xs[n * SEGc + s];
                y0 = fmaf(xv, We[s * Dd + d0], y0);
                y1 = fmaf(xv, We[s * Dd + d1], y1);
            }
            // z_n = projx(expmap0(y))
            const float yn2 = wsum64(y0 * y0 + y1 * y1);
            const float vn  = sqrtf(fmaxf(yn2, EPSF * EPSF));
            const float th  = tanhf(vn);
            float scale = th / vn;
            float nrm = th;
            if (nrm > MAXNF) { scale *= MAXNF / nrm; nrm = MAXNF; }
            z0 = y0 * scale; z1 = y1 * scale; zn2 = nrm * nrm;

            if (n > 0) {
                // v_{n-1} = logmap(z_prev, z_n)
                const float xy = -wsum64(zp0 * z0 + zp1 * z1);
                const float x2 = zpn2, y2 = zn2;
                const float c1 = 1.f + 2.f * xy + y2;
                const float c2 = 1.f - x2;
                const float den = fmaxf(1.f + 2.f * xy + x2 * y2, EPSF);
                const float u0 = (c1 * (-zp0) + c2 * z0) / den;
                const float u1 = (c1 * (-zp1) + c2 * z1) / den;
                const float un2 = wsum64(u0 * u0 + u1 * u1);
                const float un  = sqrtf(fmaxf(un2, EPSF * EPSF));
                const float lf  = fmaxf(1.f - x2, EPSF);     // 2/lam(x)
                const float g   = lf * atanhf(fminf(un, MAXNF)) / un;
                const float wj  = powf(0.9f, (float)(Nn - 1 - n)) * wnorm;
                vi0 = fmaf(wj * g, u0, vi0);
                vi1 = fmaf(wj * g, u1, vi1);
            }
            zp0 = z0; zp1 = z1; zpn2 = zn2;
        }

        // v0t = projx(expmap0(logmap0(v_init) @ Wv + bv))
        const float vin2 = wsum64(vi0 * vi0 + vi1 * vi1);
        const float vin  = sqrtf(fmaxf(vin2, EPSF * EPSF));
        const float lgv  = atanhf(fminf(vin, MAXNF)) / vin;
        __syncthreads();
        bc[d0] = lgv * vi0; bc[d1] = lgv * vi1;
        __syncthreads();
        float m0 = bv0, m1 = bv1;
        for (int k = 0; k < Dd; ++k) {
            const float tk = bc[k];
            m0 = fmaf(tk, Wv[k * Dd + d0], m0);
            m1 = fmaf(tk, Wv[k * Dd + d1], m1);
        }
        const float mn2 = wsum64(m0 * m0 + m1 * m1);
        const float mn  = sqrtf(fmaxf(mn2, EPSF * EPSF));
        const float th2 = tanhf(mn);
        float sc2 = th2 / mn;
        float v0n = th2;
        if (v0n > MAXNF) { sc2 *= MAXNF / v0n; v0n = MAXNF; }
        const float v00 = m0 * sc2, v01 = m1 * sc2;
        const float v0n2 = mn2 * sc2 * sc2;   // actual sum of squares

        const float zdotv = wsum64(z0 * v00 + z1 * v01);   // z_last . v0t
        const float x2l   = zn2;
        const float lamx  = 2.f / fmaxf(1.f - x2l, EPSF);
        const float sig   = 1.f / (1.f + expf(-steps[c]));

#pragma unroll
        for (int t = 0; t < Tt; ++t) {
            const float alpha = sig * (float)(t + 1);
            const float vtn2  = alpha * alpha * v0n2;
            const float vtn   = sqrtf(fmaxf(vtn2, EPSF * EPSF));
            const float g     = tanhf(0.5f * lamx * vtn);
            const float cyc   = g * alpha / vtn;           // y = cyc * v0t
            const float y2    = cyc * cyc * v0n2;
            const float xy    = cyc * zdotv;
            const float c1 = 1.f + 2.f * xy + y2;
            const float c2 = 1.f - x2l;
            const float den = fmaxf(1.f + 2.f * xy + x2l * y2, EPSF);
            float r0 = (c1 * z0 + c2 * cyc * v00) / den;
            float r1 = (c1 * z1 + c2 * cyc * v01) / den;
            const float rn2 = wsum64(r0 * r0 + r1 * r1);
            float rn = sqrtf(fmaxf(rn2, EPSF * EPSF));
            if (rn > MAXNF) { const float s = MAXNF / rn; r0 *= s; r1 *= s; rn = MAXNF; }
            zfl[c][t][d0] = r0; zfl[c][t][d1] = r1;
            if (lane == 0) zfns[c][t] = rn;
        }
        __syncthreads();
    }

    // softmax over mobius_w
    float mw0 = mobius_w[0], mw1 = mobius_w[1], mw2 = mobius_w[2], mw3 = mobius_w[3];
    const float mx = fmaxf(fmaxf(mw0, mw1), fmaxf(mw2, mw3));
    mw0 = expf(mw0 - mx); mw1 = expf(mw1 - mx); mw2 = expf(mw2 - mx); mw3 = expf(mw3 - mx);
    const float se = mw0 + mw1 + mw2 + mw3;
    mw0 /= se; mw1 /= se; mw2 /= se; mw3 /= se;
    const float mwv[4] = {mw0, mw1, mw2, mw3};

    // Mobius fusion + logmap0 per horizon
    for (int t = 0; t < Tt; ++t) {
        const float xn0 = zfns[0][t];
        const float s0  = tanhf(mwv[0] * atanhf(fminf(xn0, MAXNF))) / xn0;
        float cb0 = s0 * zfl[0][t][d0];
        float cb1 = s0 * zfl[0][t][d1];
        float cn2 = wsum64(cb0 * cb0 + cb1 * cb1);
#pragma unroll
        for (int i = 1; i < 4; ++i) {
            const float xni = zfns[i][t];
            const float si  = tanhf(mwv[i] * atanhf(fminf(xni, MAXNF))) / xni;
            const float yi0 = si * zfl[i][t][d0];
            const float yi1 = si * zfl[i][t][d1];
            const float y2  = wsum64(yi0 * yi0 + yi1 * yi1);
            const float xy  = wsum64(cb0 * yi0 + cb1 * yi1);
            const float c1 = 1.f + 2.f * xy + y2;
            const float c2 = 1.f - cn2;
            const float den = fmaxf(1.f + 2.f * xy + cn2 * y2, EPSF);
            cb0 = (c1 * cb0 + c2 * yi0) / den;
            cb1 = (c1 * cb1 + c2 * yi1) / den;
            cn2 = wsum64(cb0 * cb0 + cb1 * cb1);
        }
        // projx + logmap0
        float cn = sqrtf(fmaxf(cn2, EPSF * EPSF));
        if (cn > MAXNF) { const float s = MAXNF / cn; cb0 *= s; cb1 *= s; cn = MAXNF; }
        const float lg = atanhf(fminf(cn, MAXNF)) / cn;
        uls[t][d0] = lg * cb0;
        uls[t][d1] = lg * cb1;
    }

    // hinge-loss partial (lane 0 per block; deterministic final reduce in kernel 3)
    if (lane == 0) {
        float hl = 0.f;
#pragma unroll
        for (int t = 0; t < Tt; ++t) {
            float dd0 = 2.f * atanhf(fminf(zfns[0][t], MAXNF));
            float dd1 = 2.f * atanhf(fminf(zfns[1][t], MAXNF));
            float dd2 = 2.f * atanhf(fminf(zfns[2][t], MAXNF));
            float dd3 = 2.f * atanhf(fminf(zfns[3][t], MAXNF));
            hl += fmaxf(dd0 - dd1 + 0.1f, 0.f)
                + fmaxf(dd1 - dd2 + 0.1f, 0.f)
                + fmaxf(dd2 - dd3 + 0.1f, 0.f);
        }
        hpart[bf] = hl;
    }
    __syncthreads();

    // Reconstruction head: h = relu(u @ W1 + b1) ; seg = h @ W2 + b2
    float hreg[Tt][4];
#pragma unroll
    for (int t = 0; t < Tt; ++t)
#pragma unroll
        for (int q = 0; q < 4; ++q)
            hreg[t][q] = rec_b1[lane + 64 * q];
    for (int d = 0; d < Dd; ++d) {
        const float w0 = rec_W1[d * Hh + lane];
        const float w1 = rec_W1[d * Hh + lane + 64];
        const float w2 = rec_W1[d * Hh + lane + 128];
        const float w3 = rec_W1[d * Hh + lane + 192];
#pragma unroll
        for (int t = 0; t < Tt; ++t) {
            const float u = uls[t][d];
            hreg[t][0] = fmaf(u, w0, hreg[t][0]);
            hreg[t][1] = fmaf(u, w1, hreg[t][1]);
            hreg[t][2] = fmaf(u, w2, hreg[t][2]);
            hreg[t][3] = fmaf(u, w3, hreg[t][3]);
        }
    }
#pragma unroll
    for (int t = 0; t < Tt; ++t)
#pragma unroll
        for (int q = 0; q < 4; ++q)
            hbuf[t][lane + 64 * q] = fmaxf(hreg[t][q], 0.f);
    __syncthreads();

    for (int idx = lane; idx < Tt * SEGc; idx += 64) {
        const int t = idx / SEGc, s = idx % SEGc;
        float acc = rec_b2[s];
        for (int j = 0; j < Hh; ++j)
            acc = fmaf(hbuf[t][j], rec_W2[j * SEGc + s], acc);
        const float val = (acc - rb) / rw * stdv + mean;   // RevIN denorm
        out[(b * (Tt * SEGc) + idx) * Ff + f] = val;
    }
}

// ---------------- Kernel 3: deterministic hloss reduction ----------------
__global__ __launch_bounds__(256) void hloss_kernel(
    const float* __restrict__ hpart, float* __restrict__ out)
{
    __shared__ float sm[256];
    const int tid = threadIdx.x;
    float s = 0.f;
    for (int i = tid; i < BFc; i += 256) s += hpart[i];
    sm[tid] = s;
    __syncthreads();
    for (int off = 128; off > 0; off >>= 1) {
        if (tid < off) sm[tid] += sm[tid + off];
        __syncthreads();
    }
    if (tid == 0) out[Bb * Tt * SEGc * Ff] = sm[0] / (float)(BFc * Tt);
}

extern "C" void kernel_launch(void* const* d_in, const int* in_sizes, int n_in,
                              void* d_out, int out_size, void* d_ws, size_t ws_size,
                              hipStream_t stream) {
    const float* trend   = (const float*)d_in[0];
    const float* scoarse = (const float*)d_in[1];
    const float* sfine   = (const float*)d_in[2];
    const float* resid   = (const float*)d_in[3];
    const float* revin_w = (const float*)d_in[4];
    const float* revin_b = (const float*)d_in[5];
    const float* enc_W   = (const float*)d_in[6];
    const float* enc_b   = (const float*)d_in[7];
    const float* vel_W   = (const float*)d_in[8];
    const float* vel_b   = (const float*)d_in[9];
    const float* steps   = (const float*)d_in[10];
    const float* mobw    = (const float*)d_in[11];
    const float* rec_W1  = (const float*)d_in[12];
    const float* rec_b1  = (const float*)d_in[13];
    const float* rec_W2  = (const float*)d_in[14];
    const float* rec_b2  = (const float*)d_in[15];

    float* out = (float*)d_out;
    float* wsf = (float*)d_ws;           // [mean 8192][std 8192][hpart 8192]

    stats_kernel<<<Bb, Ff, 0, stream>>>(trend, scoarse, sfine, resid, wsf);
    branch_kernel<<<BFc, 64, 0, stream>>>(
        trend, scoarse, sfine, resid, revin_w, revin_b,
        enc_W, enc_b, vel_W, vel_b, steps, mobw,
        rec_W1, rec_b1, rec_W2, rec_b2,
        wsf, out, wsf + 2 * BFc);
    hloss_kernel<<<1, 256, 0, stream>>>(wsf + 2 * BFc, out);
}

// Round 2
// 526.601 us; speedup vs baseline: 1.3342x; 1.3342x over previous
//
#include <hip/hip_runtime.h>
#include <math.h>

#define EPSF 1e-5f
#define MAXNF (1.0f - 1e-5f)

constexpr int SEGc = 24;
constexpr int Nn   = 14;          // L / SEG
constexpr int NS   = Nn * SEGc;   // 336
constexpr int Tt   = 4;           // horizons
constexpr int Bb   = 32;
constexpr int Ll   = 336;
constexpr int Ff   = 256;
constexpr int Dd   = 128;
constexpr int Hh   = 256;
constexpr int BFc  = Bb * Ff;     // 8192

__device__ __forceinline__ float wsum64(float v) {
#pragma unroll
    for (int off = 1; off < 64; off <<= 1) v += __shfl_xor(v, off, 64);
    return v;  // all lanes hold the total
}

// ---------------- fused kernel: one block (4 waves) per bf ----------------
// wave wid = component c during branch phase, = horizon t during fusion.
__global__ __launch_bounds__(256) void fused_kernel(
    const float* __restrict__ trend, const float* __restrict__ scoarse,
    const float* __restrict__ sfine, const float* __restrict__ resid,
    const float* __restrict__ revin_w, const float* __restrict__ revin_b,
    const float* __restrict__ enc_W, const float* __restrict__ enc_b,
    const float* __restrict__ vel_W, const float* __restrict__ vel_b,
    const float* __restrict__ steps, const float* __restrict__ mobius_w,
    const float* __restrict__ rec_W1, const float* __restrict__ rec_b1,
    const float* __restrict__ rec_W2, const float* __restrict__ rec_b2,
    float* __restrict__ out, float* __restrict__ hpart)
{
    const int bf   = blockIdx.x;
    const int b    = bf >> 8;
    const int f    = bf & 255;
    const int tid  = threadIdx.x;
    const int wid  = tid >> 6;     // 0..3
    const int lane = tid & 63;
    const int d0 = lane, d1 = lane + 64;

    __shared__ float xs[4 * NS];       // raw->scaled comp rows; later reused as hbuf[4*Hh]
    __shared__ float bcu[4 * Dd];      // per-comp bc (branch), then per-horizon uls (fusion)
    __shared__ float zfl[4][Tt][Dd];   // z_fut
    __shared__ float zfns[4][Tt];      // clipped norms
    __shared__ float red[8];

    const float* cp = (wid == 0) ? trend : (wid == 1) ? scoarse
                    : (wid == 2) ? sfine : resid;

    // ---- stage raw component rows (each wave its component) ----
    for (int i = lane; i < NS; i += 64)
        xs[wid * NS + i] = cp[(b * Ll + i) * Ff + f];
    __syncthreads();

    // ---- RevIN stats on combined signal (in LDS, deterministic order) ----
    float sum = 0.f, sumsq = 0.f;
    for (int l = tid; l < NS; l += 256) {
        const float x = xs[l] + xs[NS + l] + xs[2 * NS + l] + xs[3 * NS + l];
        sum += x; sumsq += x * x;
    }
    sum = wsum64(sum); sumsq = wsum64(sumsq);
    if (lane == 0) { red[wid] = sum; red[4 + wid] = sumsq; }
    __syncthreads();
    sum   = red[0] + red[1] + red[2] + red[3];
    sumsq = red[4] + red[5] + red[6] + red[7];
    const float mean    = sum / (float)NS;
    const float stdv    = sqrtf(sumsq / (float)NS - mean * mean + 1e-5f);
    const float inv_std = 1.f / stdv;
    const float rw = revin_w[f], rb = revin_b[f];

    // ---- scale in place ----
    for (int i = lane; i < NS; i += 64) {
        const float raw = xs[wid * NS + i];
        xs[wid * NS + i] = ((raw - 0.25f * mean) * inv_std) * rw + 0.25f * rb;
    }
    __syncthreads();

    // ---- branch (component c = wid) ----
    const int c = wid;
    const float* xsl = xs + c * NS;
    const float* We  = enc_W + c * SEGc * Dd;
    const float* Wv  = vel_W + c * Dd * Dd;
    const float be0 = enc_b[c * Dd + d0], be1 = enc_b[c * Dd + d1];
    const float bv0 = vel_b[c * Dd + d0], bv1 = vel_b[c * Dd + d1];

    float Wsum = 0.f;
    for (int j = 0; j < Nn - 1; ++j) Wsum += powf(0.9f, (float)(Nn - 2 - j));
    const float wnorm = 1.f / (Wsum * (float)(Nn - 1));

    float vi0 = 0.f, vi1 = 0.f;
    float zp0 = 0.f, zp1 = 0.f, zpn2 = 0.f;
    float z0 = 0.f, z1 = 0.f, zn2 = 0.f;
    for (int n = 0; n < Nn; ++n) {
        float y0 = be0, y1 = be1;
        for (int s = 0; s < SEGc; ++s) {
            const float xv = xsl[n * SEGc + s];
            y0 = fmaf(xv, We[s * Dd + d0], y0);
            y1 = fmaf(xv, We[s * Dd + d1], y1);
        }
        // z_n = projx(expmap0(y))
        const float yn2 = wsum64(y0 * y0 + y1 * y1);
        const float vn  = sqrtf(fmaxf(yn2, EPSF * EPSF));
        const float th  = tanhf(vn);
        float scale = th / vn;
        float nrm = th;
        if (nrm > MAXNF) { scale *= MAXNF / nrm; nrm = MAXNF; }
        z0 = y0 * scale; z1 = y1 * scale; zn2 = nrm * nrm;

        if (n > 0) {
            // v_{n-1} = logmap(z_prev, z_n)
            const float xy = -wsum64(zp0 * z0 + zp1 * z1);
            const float x2 = zpn2, y2 = zn2;
            const float c1 = 1.f + 2.f * xy + y2;
            const float c2 = 1.f - x2;
            const float den = fmaxf(1.f + 2.f * xy + x2 * y2, EPSF);
            const float u0 = (c1 * (-zp0) + c2 * z0) / den;
            const float u1 = (c1 * (-zp1) + c2 * z1) / den;
            const float un2 = wsum64(u0 * u0 + u1 * u1);
            const float un  = sqrtf(fmaxf(un2, EPSF * EPSF));
            const float lf  = fmaxf(1.f - x2, EPSF);     // 2/lam(x)
            const float g   = lf * atanhf(fminf(un, MAXNF)) / un;
            const float wj  = powf(0.9f, (float)(Nn - 1 - n)) * wnorm;
            vi0 = fmaf(wj * g, u0, vi0);
            vi1 = fmaf(wj * g, u1, vi1);
        }
        zp0 = z0; zp1 = z1; zpn2 = zn2;
    }

    // v0t = projx(expmap0(logmap0(v_init) @ Wv + bv))
    const float vin2 = wsum64(vi0 * vi0 + vi1 * vi1);
    const float vin  = sqrtf(fmaxf(vin2, EPSF * EPSF));
    const float lgv  = atanhf(fminf(vin, MAXNF)) / vin;
    float* bc = bcu + c * Dd;          // this wave owns slice c throughout
    bc[d0] = lgv * vi0; bc[d1] = lgv * vi1;
    __syncthreads();
    float m0 = bv0, m1 = bv1;
    for (int k = 0; k < Dd; ++k) {
        const float tk = bc[k];
        m0 = fmaf(tk, Wv[k * Dd + d0], m0);
        m1 = fmaf(tk, Wv[k * Dd + d1], m1);
    }
    const float mn2 = wsum64(m0 * m0 + m1 * m1);
    const float mn  = sqrtf(fmaxf(mn2, EPSF * EPSF));
    const float th2 = tanhf(mn);
    float sc2 = th2 / mn;
    float v0n = th2;
    if (v0n > MAXNF) { sc2 *= MAXNF / v0n; v0n = MAXNF; }
    const float v00 = m0 * sc2, v01 = m1 * sc2;
    const float v0n2 = mn2 * sc2 * sc2;

    const float zdotv = wsum64(z0 * v00 + z1 * v01);   // z_last . v0t
    const float x2l   = zn2;
    const float lamx  = 2.f / fmaxf(1.f - x2l, EPSF);
    const float sig   = 1.f / (1.f + expf(-steps[c]));

#pragma unroll
    for (int t = 0; t < Tt; ++t) {
        const float alpha = sig * (float)(t + 1);
        const float vtn2  = alpha * alpha * v0n2;
        const float vtn   = sqrtf(fmaxf(vtn2, EPSF * EPSF));
        const float g     = tanhf(0.5f * lamx * vtn);
        const float cyc   = g * alpha / vtn;           // y = cyc * v0t
        const float y2    = cyc * cyc * v0n2;
        const float xy    = cyc * zdotv;
        const float c1 = 1.f + 2.f * xy + y2;
        const float c2 = 1.f - x2l;
        const float den = fmaxf(1.f + 2.f * xy + x2l * y2, EPSF);
        float r0 = (c1 * z0 + c2 * cyc * v00) / den;
        float r1 = (c1 * z1 + c2 * cyc * v01) / den;
        const float rn2 = wsum64(r0 * r0 + r1 * r1);
        float rn = sqrtf(fmaxf(rn2, EPSF * EPSF));
        if (rn > MAXNF) { const float s = MAXNF / rn; r0 *= s; r1 *= s; rn = MAXNF; }
        zfl[c][t][d0] = r0; zfl[c][t][d1] = r1;
        if (lane == 0) zfns[c][t] = rn;
    }
    __syncthreads();

    // ---- Mobius fusion: wave wid handles horizon t = wid ----
    {
        float mw0 = mobius_w[0], mw1 = mobius_w[1], mw2 = mobius_w[2], mw3 = mobius_w[3];
        const float mx = fmaxf(fmaxf(mw0, mw1), fmaxf(mw2, mw3));
        mw0 = expf(mw0 - mx); mw1 = expf(mw1 - mx); mw2 = expf(mw2 - mx); mw3 = expf(mw3 - mx);
        const float se = mw0 + mw1 + mw2 + mw3;
        const float mwv[4] = {mw0 / se, mw1 / se, mw2 / se, mw3 / se};

        const int t = wid;
        const float xn0 = zfns[0][t];
        const float s0  = tanhf(mwv[0] * atanhf(fminf(xn0, MAXNF))) / xn0;
        float cb0 = s0 * zfl[0][t][d0];
        float cb1 = s0 * zfl[0][t][d1];
        float cn2 = wsum64(cb0 * cb0 + cb1 * cb1);
#pragma unroll
        for (int i = 1; i < 4; ++i) {
            const float xni = zfns[i][t];
            const float si  = tanhf(mwv[i] * atanhf(fminf(xni, MAXNF))) / xni;
            const float yi0 = si * zfl[i][t][d0];
            const float yi1 = si * zfl[i][t][d1];
            const float y2  = wsum64(yi0 * yi0 + yi1 * yi1);
            const float xy  = wsum64(cb0 * yi0 + cb1 * yi1);
            const float c1 = 1.f + 2.f * xy + y2;
            const float c2 = 1.f - cn2;
            const float den = fmaxf(1.f + 2.f * xy + cn2 * y2, EPSF);
            cb0 = (c1 * cb0 + c2 * yi0) / den;
            cb1 = (c1 * cb1 + c2 * yi1) / den;
            cn2 = wsum64(cb0 * cb0 + cb1 * cb1);
        }
        float cn = sqrtf(fmaxf(cn2, EPSF * EPSF));
        if (cn > MAXNF) { const float s = MAXNF / cn; cb0 *= s; cb1 *= s; cn = MAXNF; }
        const float lg = atanhf(fminf(cn, MAXNF)) / cn;
        // uls lives in bcu (this wave owns slice t = wid)
        bcu[t * Dd + d0] = lg * cb0;
        bcu[t * Dd + d1] = lg * cb1;
    }

    // ---- hinge-loss partial ----
    if (tid == 0) {
        float hl = 0.f;
#pragma unroll
        for (int t = 0; t < Tt; ++t) {
            const float dd0 = 2.f * atanhf(fminf(zfns[0][t], MAXNF));
            const float dd1 = 2.f * atanhf(fminf(zfns[1][t], MAXNF));
            const float dd2 = 2.f * atanhf(fminf(zfns[2][t], MAXNF));
            const float dd3 = 2.f * atanhf(fminf(zfns[3][t], MAXNF));
            hl += fmaxf(dd0 - dd1 + 0.1f, 0.f)
                + fmaxf(dd1 - dd2 + 0.1f, 0.f)
                + fmaxf(dd2 - dd3 + 0.1f, 0.f);
        }
        hpart[bf] = hl;
    }
    __syncthreads();

    // ---- reconstruction head, all 256 threads: h[t][j], j = tid ----
    {
        const int j = tid;
        float a0 = rec_b1[j], a1 = a0, a2 = a0, a3 = a0;
        for (int k = 0; k < Dd; ++k) {
            const float w = rec_W1[k * Hh + j];
            a0 = fmaf(bcu[0 * Dd + k], w, a0);
            a1 = fmaf(bcu[1 * Dd + k], w, a1);
            a2 = fmaf(bcu[2 * Dd + k], w, a2);
            a3 = fmaf(bcu[3 * Dd + k], w, a3);
        }
        __syncthreads();  // xs no longer needed; reuse as hbuf
        xs[0 * Hh + j] = fmaxf(a0, 0.f);
        xs[1 * Hh + j] = fmaxf(a1, 0.f);
        xs[2 * Hh + j] = fmaxf(a2, 0.f);
        xs[3 * Hh + j] = fmaxf(a3, 0.f);
    }
    __syncthreads();

    // ---- seg outputs: 96 of them, threads 0..95 ----
    if (tid < Tt * SEGc) {
        const int t = tid / SEGc, s = tid - t * SEGc;
        float acc = rec_b2[s];
        for (int j = 0; j < Hh; ++j)
            acc = fmaf(xs[t * Hh + j], rec_W2[j * SEGc + s], acc);
        const float val = (acc - rb) / rw * stdv + mean;   // RevIN denorm
        out[(b * (Tt * SEGc) + tid) * Ff + f] = val;
    }
}

// ---------------- deterministic hloss reduction ----------------
__global__ __launch_bounds__(256) void hloss_kernel(
    const float* __restrict__ hpart, float* __restrict__ out)
{
    __shared__ float sm[256];
    const int tid = threadIdx.x;
    float s = 0.f;
    for (int i = tid; i < BFc; i += 256) s += hpart[i];
    sm[tid] = s;
    __syncthreads();
    for (int off = 128; off > 0; off >>= 1) {
        if (tid < off) sm[tid] += sm[tid + off];
        __syncthreads();
    }
    if (tid == 0) out[Bb * Tt * SEGc * Ff] = sm[0] / (float)(BFc * Tt);
}

extern "C" void kernel_launch(void* const* d_in, const int* in_sizes, int n_in,
                              void* d_out, int out_size, void* d_ws, size_t ws_size,
                              hipStream_t stream) {
    const float* trend   = (const float*)d_in[0];
    const float* scoarse = (const float*)d_in[1];
    const float* sfine   = (const float*)d_in[2];
    const float* resid   = (const float*)d_in[3];
    const float* revin_w = (const float*)d_in[4];
    const float* revin_b = (const float*)d_in[5];
    const float* enc_W   = (const float*)d_in[6];
    const float* enc_b   = (const float*)d_in[7];
    const float* vel_W   = (const float*)d_in[8];
    const float* vel_b   = (const float*)d_in[9];
    const float* steps   = (const float*)d_in[10];
    const float* mobw    = (const float*)d_in[11];
    const float* rec_W1  = (const float*)d_in[12];
    const float* rec_b1  = (const float*)d_in[13];
    const float* rec_W2  = (const float*)d_in[14];
    const float* rec_b2  = (const float*)d_in[15];

    float* out = (float*)d_out;
    float* wsf = (float*)d_ws;           // hpart[8192]

    fused_kernel<<<BFc, 256, 0, stream>>>(
        trend, scoarse, sfine, resid, revin_w, revin_b,
        enc_W, enc_b, vel_W, vel_b, steps, mobw,
        rec_W1, rec_b1, rec_W2, rec_b2,
        out, wsf);
    hloss_kernel<<<1, 256, 0, stream>>>(wsf, out);
}

// Round 3
// 341.738 us; speedup vs baseline: 2.0560x; 1.5409x over previous
//
#include <hip/hip_runtime.h>
#include <math.h>

#define EPSF 1e-5f
#define MAXNF (1.0f - 1e-5f)

constexpr int SEGc = 24;
constexpr int Nn   = 14;          // L / SEG
constexpr int NS   = Nn * SEGc;   // 336
constexpr int Tt   = 4;           // horizons
constexpr int Bb   = 32;
constexpr int Ll   = 336;
constexpr int Ff   = 256;
constexpr int Dd   = 128;
constexpr int Hh   = 256;
constexpr int BFc  = Bb * Ff;     // 8192

// ---- fast math (tolerance 1.8e-2; these are ~1e-7 relative) ----
__device__ __forceinline__ float frcp(float x)  { return __builtin_amdgcn_rcpf(x); }
__device__ __forceinline__ float fsqrtf_(float x){ return __builtin_amdgcn_sqrtf(x); }
__device__ __forceinline__ float ftanh_pos(float x) {       // x >= 0
    const float e = __expf(fminf(2.f * x, 30.f));           // v_exp_f32
    return (e - 1.f) * frcp(e + 1.f);
}
__device__ __forceinline__ float fatanh01(float x) {        // 0 <= x <= MAXNF
    return 0.5f * __logf((1.f + x) * frcp(1.f - x));        // v_log_f32
}

__device__ __forceinline__ float wsum64(float v) {
#pragma unroll
    for (int off = 1; off < 64; off <<= 1) v += __shfl_xor(v, off, 64);
    return v;  // all lanes hold the total
}

// ---------------- fused kernel: one block (4 waves) per bf ----------------
// wave wid = component c during branch phase, = horizon t during fusion.
// lane owns dims d0=2*lane, d1=2*lane+1 (so weight loads are float2).
__global__ __launch_bounds__(256) void fused_kernel(
    const float* __restrict__ trend, const float* __restrict__ scoarse,
    const float* __restrict__ sfine, const float* __restrict__ resid,
    const float* __restrict__ revin_w, const float* __restrict__ revin_b,
    const float* __restrict__ enc_W, const float* __restrict__ enc_b,
    const float* __restrict__ vel_W, const float* __restrict__ vel_b,
    const float* __restrict__ steps, const float* __restrict__ mobius_w,
    const float* __restrict__ rec_W1, const float* __restrict__ rec_b1,
    const float* __restrict__ rec_W2, const float* __restrict__ rec_b2,
    float* __restrict__ out, float* __restrict__ hpart)
{
    const int bf   = blockIdx.x;
    const int b    = bf >> 8;
    const int f    = bf & 255;
    const int tid  = threadIdx.x;
    const int wid  = tid >> 6;     // 0..3
    const int lane = tid & 63;

    __shared__ float xs[4 * NS];       // scaled comp rows; later reused as hbuf[4*Hh]
    __shared__ float bcu[4 * Dd];      // per-comp bc (branch), then per-horizon uls (fusion)
    __shared__ float zfl[4][Tt][Dd];   // z_fut
    __shared__ float zfns[4][Tt];      // clipped norms
    __shared__ float red[8];

    const float* cp = (wid == 0) ? trend : (wid == 1) ? scoarse
                    : (wid == 2) ? sfine : resid;

    // ---- stage raw component rows (each wave its component) ----
    for (int i = lane; i < NS; i += 64)
        xs[wid * NS + i] = cp[(b * Ll + i) * Ff + f];
    __syncthreads();

    // ---- RevIN stats on combined signal ----
    float sum = 0.f, sumsq = 0.f;
    for (int l = tid; l < NS; l += 256) {
        const float x = xs[l] + xs[NS + l] + xs[2 * NS + l] + xs[3 * NS + l];
        sum += x; sumsq += x * x;
    }
    sum = wsum64(sum); sumsq = wsum64(sumsq);
    if (lane == 0) { red[wid] = sum; red[4 + wid] = sumsq; }
    __syncthreads();
    sum   = red[0] + red[1] + red[2] + red[3];
    sumsq = red[4] + red[5] + red[6] + red[7];
    const float mean    = sum * (1.f / (float)NS);
    const float stdv    = fsqrtf_(sumsq * (1.f / (float)NS) - mean * mean + 1e-5f);
    const float inv_std = frcp(stdv);
    const float rw = revin_w[f], rb = revin_b[f];

    // ---- scale own slice in place (own-wave; branch reads own slice) ----
    for (int i = lane; i < NS; i += 64) {
        const float raw = xs[wid * NS + i];
        xs[wid * NS + i] = ((raw - 0.25f * mean) * inv_std) * rw + 0.25f * rb;
    }

    // ---- branch (component c = wid) ----
    const int c = wid;
    const float4* xv4 = reinterpret_cast<const float4*>(xs + c * NS);
    const float* Wep  = enc_W + c * SEGc * Dd + 2 * lane;
    const float* Wvp  = vel_W + c * Dd * Dd + 2 * lane;

    float2 wreg[SEGc];                       // hoist encoder weights: 48 VGPRs
#pragma unroll
    for (int s = 0; s < SEGc; ++s)
        wreg[s] = *reinterpret_cast<const float2*>(Wep + s * Dd);
    const float2 be = *reinterpret_cast<const float2*>(enc_b + c * Dd + 2 * lane);
    const float2 bv = *reinterpret_cast<const float2*>(vel_b + c * Dd + 2 * lane);

    // w_j = 0.9^(13-n) * wnorm, wnorm = 1/(sum_{i=0}^{12} 0.9^i * 13)
    const float wnorm = 1.f / (7.4581341716711f * 13.f);
    float wj = 0.282429536481f * wnorm;      // 0.9^12 * wnorm  (used first at n=1)

    float vi0 = 0.f, vi1 = 0.f;
    float zp0 = 0.f, zp1 = 0.f, zpn2 = 0.f;
    float z0 = 0.f, z1 = 0.f, zn2 = 0.f;
    for (int n = 0; n < Nn; ++n) {
        float y0 = be.x, y1 = be.y;
#pragma unroll
        for (int q = 0; q < SEGc / 4; ++q) {
            const float4 xv = xv4[n * (SEGc / 4) + q];
            y0 = fmaf(xv.x, wreg[4*q+0].x, y0); y1 = fmaf(xv.x, wreg[4*q+0].y, y1);
            y0 = fmaf(xv.y, wreg[4*q+1].x, y0); y1 = fmaf(xv.y, wreg[4*q+1].y, y1);
            y0 = fmaf(xv.z, wreg[4*q+2].x, y0); y1 = fmaf(xv.z, wreg[4*q+2].y, y1);
            y0 = fmaf(xv.w, wreg[4*q+3].x, y0); y1 = fmaf(xv.w, wreg[4*q+3].y, y1);
        }
        // z_n = projx(expmap0(y))
        const float yn2 = wsum64(y0 * y0 + y1 * y1);
        const float vn  = fsqrtf_(fmaxf(yn2, EPSF * EPSF));
        const float th  = ftanh_pos(vn);
        float scale = th * frcp(vn);
        float nrm = th;
        if (nrm > MAXNF) { scale *= MAXNF * frcp(nrm); nrm = MAXNF; }
        z0 = y0 * scale; z1 = y1 * scale; zn2 = nrm * nrm;

        if (n > 0) {
            // v_{n-1} = logmap(z_prev, z_n)
            const float xy = -wsum64(zp0 * z0 + zp1 * z1);
            const float x2 = zpn2, y2 = zn2;
            const float c1 = 1.f + 2.f * xy + y2;
            const float c2 = 1.f - x2;
            const float rden = frcp(fmaxf(1.f + 2.f * xy + x2 * y2, EPSF));
            const float u0 = (c1 * (-zp0) + c2 * z0) * rden;
            const float u1 = (c1 * (-zp1) + c2 * z1) * rden;
            const float un2 = wsum64(u0 * u0 + u1 * u1);
            const float un  = fsqrtf_(fmaxf(un2, EPSF * EPSF));
            const float lf  = fmaxf(1.f - x2, EPSF);     // 2/lam(x)
            const float g   = lf * fatanh01(fminf(un, MAXNF)) * frcp(un);
            const float gw  = wj * g;
            vi0 = fmaf(gw, u0, vi0);
            vi1 = fmaf(gw, u1, vi1);
            wj *= (1.f / 0.9f);
        }
        zp0 = z0; zp1 = z1; zpn2 = zn2;
    }

    // v0t = projx(expmap0(logmap0(v_init) @ Wv + bv))
    const float vin2 = wsum64(vi0 * vi0 + vi1 * vi1);
    const float vin  = fsqrtf_(fmaxf(vin2, EPSF * EPSF));
    const float lgv  = fatanh01(fminf(vin, MAXNF)) * frcp(vin);
    float* bc = bcu + c * Dd;
    *reinterpret_cast<float2*>(bc + 2 * lane) = make_float2(lgv * vi0, lgv * vi1);
    __syncthreads();   // cheap; guarantees cross-lane LDS visibility before broadcast reads

    float m0 = bv.x, m1 = bv.y;
    {
        const float4* bc4 = reinterpret_cast<const float4*>(bc);
#pragma unroll 4
        for (int k4 = 0; k4 < Dd / 4; ++k4) {
            const float4 t4 = bc4[k4];
            const float2 w0 = *reinterpret_cast<const float2*>(Wvp + (4*k4+0) * Dd);
            const float2 w1 = *reinterpret_cast<const float2*>(Wvp + (4*k4+1) * Dd);
            const float2 w2 = *reinterpret_cast<const float2*>(Wvp + (4*k4+2) * Dd);
            const float2 w3 = *reinterpret_cast<const float2*>(Wvp + (4*k4+3) * Dd);
            m0 = fmaf(t4.x, w0.x, m0); m1 = fmaf(t4.x, w0.y, m1);
            m0 = fmaf(t4.y, w1.x, m0); m1 = fmaf(t4.y, w1.y, m1);
            m0 = fmaf(t4.z, w2.x, m0); m1 = fmaf(t4.z, w2.y, m1);
            m0 = fmaf(t4.w, w3.x, m0); m1 = fmaf(t4.w, w3.y, m1);
        }
    }
    const float mn2 = wsum64(m0 * m0 + m1 * m1);
    const float mn  = fsqrtf_(fmaxf(mn2, EPSF * EPSF));
    const float th2 = ftanh_pos(mn);
    float sc2 = th2 * frcp(mn);
    float v0n = th2;
    if (v0n > MAXNF) { sc2 *= MAXNF * frcp(v0n); v0n = MAXNF; }
    const float v00 = m0 * sc2, v01 = m1 * sc2;
    const float v0n2 = mn2 * sc2 * sc2;

    const float zdotv = wsum64(z0 * v00 + z1 * v01);   // z_last . v0t
    const float x2l   = zn2;
    const float lamx  = 2.f * frcp(fmaxf(1.f - x2l, EPSF));
    const float sig   = frcp(1.f + __expf(-steps[c]));

#pragma unroll
    for (int t = 0; t < Tt; ++t) {
        const float alpha = sig * (float)(t + 1);
        const float vtn2  = alpha * alpha * v0n2;
        const float vtn   = fsqrtf_(fmaxf(vtn2, EPSF * EPSF));
        const float g     = ftanh_pos(0.5f * lamx * vtn);
        const float cyc   = g * alpha * frcp(vtn);     // y = cyc * v0t
        const float y2    = cyc * cyc * v0n2;
        const float xy    = cyc * zdotv;
        const float c1 = 1.f + 2.f * xy + y2;
        const float c2 = 1.f - x2l;
        const float rden = frcp(fmaxf(1.f + 2.f * xy + x2l * y2, EPSF));
        float r0 = (c1 * z0 + c2 * cyc * v00) * rden;
        float r1 = (c1 * z1 + c2 * cyc * v01) * rden;
        const float rn2 = wsum64(r0 * r0 + r1 * r1);
        float rn = fsqrtf_(fmaxf(rn2, EPSF * EPSF));
        if (rn > MAXNF) { const float s = MAXNF * frcp(rn); r0 *= s; r1 *= s; rn = MAXNF; }
        *reinterpret_cast<float2*>(&zfl[c][t][2 * lane]) = make_float2(r0, r1);
        if (lane == 0) zfns[c][t] = rn;
    }
    __syncthreads();

    // ---- Mobius fusion: wave wid handles horizon t = wid ----
    {
        float mw0 = mobius_w[0], mw1 = mobius_w[1], mw2 = mobius_w[2], mw3 = mobius_w[3];
        const float mx = fmaxf(fmaxf(mw0, mw1), fmaxf(mw2, mw3));
        mw0 = __expf(mw0 - mx); mw1 = __expf(mw1 - mx);
        mw2 = __expf(mw2 - mx); mw3 = __expf(mw3 - mx);
        const float rse = frcp(mw0 + mw1 + mw2 + mw3);
        const float mwv[4] = {mw0 * rse, mw1 * rse, mw2 * rse, mw3 * rse};

        const int t = wid;
        const float xn0 = zfns[0][t];
        const float s0  = ftanh_pos(mwv[0] * fatanh01(xn0)) * frcp(xn0);
        const float2 zz0 = *reinterpret_cast<const float2*>(&zfl[0][t][2 * lane]);
        float cb0 = s0 * zz0.x;
        float cb1 = s0 * zz0.y;
        float cn2 = wsum64(cb0 * cb0 + cb1 * cb1);
#pragma unroll
        for (int i = 1; i < 4; ++i) {
            const float xni = zfns[i][t];
            const float si  = ftanh_pos(mwv[i] * fatanh01(xni)) * frcp(xni);
            const float2 zi = *reinterpret_cast<const float2*>(&zfl[i][t][2 * lane]);
            const float yi0 = si * zi.x, yi1 = si * zi.y;
            const float y2  = wsum64(yi0 * yi0 + yi1 * yi1);
            const float xy  = wsum64(cb0 * yi0 + cb1 * yi1);
            const float c1 = 1.f + 2.f * xy + y2;
            const float c2 = 1.f - cn2;
            const float rden = frcp(fmaxf(1.f + 2.f * xy + cn2 * y2, EPSF));
            cb0 = (c1 * cb0 + c2 * yi0) * rden;
            cb1 = (c1 * cb1 + c2 * yi1) * rden;
            cn2 = wsum64(cb0 * cb0 + cb1 * cb1);
        }
        float cn = fsqrtf_(fmaxf(cn2, EPSF * EPSF));
        if (cn > MAXNF) { const float s = MAXNF * frcp(cn); cb0 *= s; cb1 *= s; cn = MAXNF; }
        const float lg = fatanh01(cn) * frcp(cn);
        *reinterpret_cast<float2*>(&bcu[t * Dd + 2 * lane]) = make_float2(lg * cb0, lg * cb1);
    }

    // ---- hinge-loss partial (wave 0, parallel over 16 (comp,t) pairs) ----
    if (wid == 0) {
        float ddv = 0.f;
        if (lane < 16)
            ddv = 2.f * fatanh01(zfns[lane & 3][lane >> 2]);
        const float ddn = __shfl(ddv, lane + 1, 64);      // next comp, same t
        float hv = ((lane < 16) && ((lane & 3) != 3))
                 ? fmaxf(ddv - ddn + 0.1f, 0.f) : 0.f;
        hv = wsum64(hv);
        if (lane == 0) hpart[bf] = hv;
    }
    __syncthreads();

    // ---- reconstruction head, all 256 threads: h[t][j], j = tid ----
    {
        const float4* u4 = reinterpret_cast<const float4*>(bcu);
        float a0 = rec_b1[tid], a1 = a0, a2 = a0, a3 = a0;
        const float* w1p = rec_W1 + tid;
#pragma unroll 4
        for (int k4 = 0; k4 < Dd / 4; ++k4) {
            const float4 u0 = u4[0 * (Dd/4) + k4];
            const float4 u1 = u4[1 * (Dd/4) + k4];
            const float4 u2 = u4[2 * (Dd/4) + k4];
            const float4 u3 = u4[3 * (Dd/4) + k4];
            const float wa = w1p[(4*k4+0) * Hh];
            const float wb = w1p[(4*k4+1) * Hh];
            const float wc = w1p[(4*k4+2) * Hh];
            const float wd = w1p[(4*k4+3) * Hh];
            a0 = fmaf(u0.x, wa, a0); a0 = fmaf(u0.y, wb, a0);
            a0 = fmaf(u0.z, wc, a0); a0 = fmaf(u0.w, wd, a0);
            a1 = fmaf(u1.x, wa, a1); a1 = fmaf(u1.y, wb, a1);
            a1 = fmaf(u1.z, wc, a1); a1 = fmaf(u1.w, wd, a1);
            a2 = fmaf(u2.x, wa, a2); a2 = fmaf(u2.y, wb, a2);
            a2 = fmaf(u2.z, wc, a2); a2 = fmaf(u2.w, wd, a2);
            a3 = fmaf(u3.x, wa, a3); a3 = fmaf(u3.y, wb, a3);
            a3 = fmaf(u3.z, wc, a3); a3 = fmaf(u3.w, wd, a3);
        }
        // xs no longer read by anyone; reuse as hbuf
        xs[0 * Hh + tid] = fmaxf(a0, 0.f);
        xs[1 * Hh + tid] = fmaxf(a1, 0.f);
        xs[2 * Hh + tid] = fmaxf(a2, 0.f);
        xs[3 * Hh + tid] = fmaxf(a3, 0.f);
    }
    __syncthreads();

    // ---- seg outputs: 96 of them, threads 0..95 ----
    if (tid < Tt * SEGc) {
        const int t = tid / SEGc, s = tid - t * SEGc;
        const float4* h4 = reinterpret_cast<const float4*>(xs + t * Hh);
        const float* w2p = rec_W2 + s;
        float acc = rec_b2[s];
#pragma unroll 4
        for (int j4 = 0; j4 < Hh / 4; ++j4) {
            const float4 h = h4[j4];
            acc = fmaf(h.x, w2p[(4*j4+0) * SEGc], acc);
            acc = fmaf(h.y, w2p[(4*j4+1) * SEGc], acc);
            acc = fmaf(h.z, w2p[(4*j4+2) * SEGc], acc);
            acc = fmaf(h.w, w2p[(4*j4+3) * SEGc], acc);
        }
        const float val = (acc - rb) * frcp(rw) * stdv + mean;   // RevIN denorm
        out[(b * (Tt * SEGc) + tid) * Ff + f] = val;
    }
}

// ---------------- deterministic hloss reduction ----------------
__global__ __launch_bounds__(256) void hloss_kernel(
    const float* __restrict__ hpart, float* __restrict__ out)
{
    __shared__ float sm[256];
    const int tid = threadIdx.x;
    float s = 0.f;
    for (int i = tid; i < BFc; i += 256) s += hpart[i];
    sm[tid] = s;
    __syncthreads();
    for (int off = 128; off > 0; off >>= 1) {
        if (tid < off) sm[tid] += sm[tid + off];
        __syncthreads();
    }
    if (tid == 0) out[Bb * Tt * SEGc * Ff] = sm[0] / (float)(BFc * Tt);
}

extern "C" void kernel_launch(void* const* d_in, const int* in_sizes, int n_in,
                              void* d_out, int out_size, void* d_ws, size_t ws_size,
                              hipStream_t stream) {
    const float* trend   = (const float*)d_in[0];
    const float* scoarse = (const float*)d_in[1];
    const float* sfine   = (const float*)d_in[2];
    const float* resid   = (const float*)d_in[3];
    const float* revin_w = (const float*)d_in[4];
    const float* revin_b = (const float*)d_in[5];
    const float* enc_W   = (const float*)d_in[6];
    const float* enc_b   = (const float*)d_in[7];
    const float* vel_W   = (const float*)d_in[8];
    const float* vel_b   = (const float*)d_in[9];
    const float* steps   = (const float*)d_in[10];
    const float* mobw    = (const float*)d_in[11];
    const float* rec_W1  = (const float*)d_in[12];
    const float* rec_b1  = (const float*)d_in[13];
    const float* rec_W2  = (const float*)d_in[14];
    const float* rec_b2  = (const float*)d_in[15];

    float* out = (float*)d_out;
    float* wsf = (float*)d_ws;           // hpart[8192]

    fused_kernel<<<BFc, 256, 0, stream>>>(
        trend, scoarse, sfine, resid, revin_w, revin_b,
        enc_W, enc_b, vel_W, vel_b, steps, mobw,
        rec_W1, rec_b1, rec_W2, rec_b2,
        out, wsf);
    hloss_kernel<<<1, 256, 0, stream>>>(wsf, out);
}

// Round 4
// 311.184 us; speedup vs baseline: 2.2579x; 1.0982x over previous
//
#include <hip/hip_runtime.h>
#include <math.h>

#define EPSF 1e-5f
#define MAXNF (1.0f - 1e-5f)

constexpr int SEGc = 24;
constexpr int Nn   = 14;          // L / SEG
constexpr int NS   = Nn * SEGc;   // 336
constexpr int Tt   = 4;           // horizons
constexpr int Bb   = 32;
constexpr int Ll   = 336;
constexpr int Ff   = 256;
constexpr int Dd   = 128;
constexpr int Hh   = 256;
constexpr int BFc  = Bb * Ff;     // 8192

// ---- fast math (tolerance 1.8e-2; these are ~1e-7 relative) ----
__device__ __forceinline__ float frcp(float x)  { return __builtin_amdgcn_rcpf(x); }
__device__ __forceinline__ float fsqrtf_(float x){ return __builtin_amdgcn_sqrtf(x); }
__device__ __forceinline__ float ftanh_pos(float x) {       // x >= 0
    const float e = __expf(fminf(2.f * x, 30.f));           // v_exp_f32
    return (e - 1.f) * frcp(e + 1.f);
}
__device__ __forceinline__ float fatanh01(float x) {        // 0 <= x <= MAXNF
    return 0.5f * __logf((1.f + x) * frcp(1.f - x));        // v_log_f32
}

__device__ __forceinline__ float wsum64(float v) {
#pragma unroll
    for (int off = 1; off < 64; off <<= 1) v += __shfl_xor(v, off, 64);
    return v;
}

// ---------------- fused kernel: one block (4 waves) per bf ----------------
// wave wid = component c during branch phase, = horizon t during fusion.
// lane owns dims d0=2*lane, d1=2*lane+1.
__global__ __launch_bounds__(256) void fused_kernel(
    const float* __restrict__ trend, const float* __restrict__ scoarse,
    const float* __restrict__ sfine, const float* __restrict__ resid,
    const float* __restrict__ revin_w, const float* __restrict__ revin_b,
    const float* __restrict__ enc_W, const float* __restrict__ enc_b,
    const float* __restrict__ vel_W, const float* __restrict__ vel_b,
    const float* __restrict__ steps, const float* __restrict__ mobius_w,
    const float* __restrict__ rec_W1, const float* __restrict__ rec_b1,
    const float* __restrict__ rec_W2, const float* __restrict__ rec_b2,
    float* __restrict__ out, float* __restrict__ hpart)
{
    const int bf   = blockIdx.x;
    const int b    = bf >> 8;
    const int f    = bf & 255;
    const int tid  = threadIdx.x;
    const int wid  = tid >> 6;     // 0..3
    const int lane = tid & 63;

    __shared__ float xs[4 * NS];       // scaled comp rows; later reused as hbuf[4*Hh]
    __shared__ float bcu[4 * Dd];      // per-comp bc (branch), then per-horizon uls (fusion)
    __shared__ float zfl[4][Tt][Dd];   // z_fut
    __shared__ float zfns[4][Tt];      // clipped norms
    __shared__ float red[8];

    const float* cp = (wid == 0) ? trend : (wid == 1) ? scoarse
                    : (wid == 2) ? sfine : resid;

    // ---- stage raw component rows (each wave its component) ----
    for (int i = lane; i < NS; i += 64)
        xs[wid * NS + i] = cp[(b * Ll + i) * Ff + f];
    __syncthreads();

    // ---- RevIN stats on combined signal ----
    float sum = 0.f, sumsq = 0.f;
    for (int l = tid; l < NS; l += 256) {
        const float x = xs[l] + xs[NS + l] + xs[2 * NS + l] + xs[3 * NS + l];
        sum += x; sumsq += x * x;
    }
    sum = wsum64(sum); sumsq = wsum64(sumsq);
    if (lane == 0) { red[wid] = sum; red[4 + wid] = sumsq; }
    __syncthreads();
    sum   = red[0] + red[1] + red[2] + red[3];
    sumsq = red[4] + red[5] + red[6] + red[7];
    const float mean    = sum * (1.f / (float)NS);
    const float stdv    = fsqrtf_(sumsq * (1.f / (float)NS) - mean * mean + 1e-5f);
    const float inv_std = frcp(stdv);
    const float rw = revin_w[f], rb = revin_b[f];

    // ---- scale own slice in place (branch reads only own slice) ----
    for (int i = lane; i < NS; i += 64) {
        const float raw = xs[wid * NS + i];
        xs[wid * NS + i] = ((raw - 0.25f * mean) * inv_std) * rw + 0.25f * rb;
    }

    // ================= branch (component c = wid) =================
    const int c = wid;
    const float4* xv4 = reinterpret_cast<const float4*>(xs + c * NS);
    const float* Wep  = enc_W + c * SEGc * Dd + 2 * lane;
    const float* Wvp  = vel_W + c * Dd * Dd + 2 * lane;

    float2 wreg[SEGc];
#pragma unroll
    for (int s = 0; s < SEGc; ++s)
        wreg[s] = *reinterpret_cast<const float2*>(Wep + s * Dd);
    const float2 be = *reinterpret_cast<const float2*>(enc_b + c * Dd + 2 * lane);
    const float2 bv = *reinterpret_cast<const float2*>(vel_b + c * Dd + 2 * lane);

    // --- Phase A: all 14 encoder dots (independent) ---
    float y0[Nn], y1[Nn], qn[Nn];
#pragma unroll
    for (int n = 0; n < Nn; ++n) {
        float a = be.x, d = be.y;
#pragma unroll
        for (int q = 0; q < SEGc / 4; ++q) {
            const float4 xv = xv4[n * (SEGc / 4) + q];
            a = fmaf(xv.x, wreg[4*q+0].x, a); d = fmaf(xv.x, wreg[4*q+0].y, d);
            a = fmaf(xv.y, wreg[4*q+1].x, a); d = fmaf(xv.y, wreg[4*q+1].y, d);
            a = fmaf(xv.z, wreg[4*q+2].x, a); d = fmaf(xv.z, wreg[4*q+2].y, d);
            a = fmaf(xv.w, wreg[4*q+3].x, a); d = fmaf(xv.w, wreg[4*q+3].y, d);
        }
        y0[n] = a; y1[n] = d; qn[n] = a * a + d * d;
    }
    // --- batched butterfly: 14 independent reductions, pipelined per stage ---
#pragma unroll
    for (int off = 1; off < 64; off <<= 1) {
#pragma unroll
        for (int n = 0; n < Nn; ++n) qn[n] += __shfl_xor(qn[n], off, 64);
    }
    // --- per-n scalars (independent, high ILP): scale + norm2 ---
    float sc[Nn], zn2a[Nn];
#pragma unroll
    for (int n = 0; n < Nn; ++n) {
        const float vn = fsqrtf_(fmaxf(qn[n], EPSF * EPSF));
        const float th = ftanh_pos(vn);
        float s = th * frcp(vn);
        float nrm = th;
        if (nrm > MAXNF) { s *= MAXNF * frcp(nrm); nrm = MAXNF; }
        sc[n] = s; zn2a[n] = nrm * nrm;
    }
    // --- neighbor dots y_{n-1}.y_n, batched butterfly ---
    float rd[Nn - 1];
#pragma unroll
    for (int n = 1; n < Nn; ++n)
        rd[n - 1] = y0[n - 1] * y0[n] + y1[n - 1] * y1[n];
#pragma unroll
    for (int off = 1; off < 64; off <<= 1) {
#pragma unroll
        for (int j = 0; j < Nn - 1; ++j) rd[j] += __shfl_xor(rd[j], off, 64);
    }
    // --- logmap chain, all scalar (analytic |u|^2), fold into coef[n] ---
    const float wnorm = 1.f / (7.4581341716711f * 13.f);
    float wj = 0.282429536481f * wnorm;      // 0.9^12 * wnorm, first used at j=1
    float coef[Nn];
#pragma unroll
    for (int n = 0; n < Nn; ++n) coef[n] = 0.f;
#pragma unroll
    for (int j = 1; j < Nn; ++j) {
        const float xy  = -(sc[j-1] * sc[j] * rd[j-1]);     // matches -wsum(zp.z)
        const float x2  = zn2a[j-1], yy2 = zn2a[j];
        const float c1  = 1.f + 2.f * xy + yy2;
        const float c2  = 1.f - x2;
        const float rden = frcp(fmaxf(1.f + 2.f * xy + x2 * yy2, EPSF));
        // |u|^2 = rden^2 (c1^2|zp|^2 - 2 c1 c2 (zp.z) + c2^2|z|^2), (zp.z) = -xy
        const float un2 = rden * rden *
            (c1 * c1 * x2 + 2.f * c1 * c2 * xy + c2 * c2 * yy2);
        const float un  = fsqrtf_(fmaxf(un2, EPSF * EPSF));
        const float lf  = fmaxf(1.f - x2, EPSF);            // 2/lam
        const float g   = lf * fatanh01(fminf(un, MAXNF)) * frcp(un);
        const float gw  = wj * g * rden;
        coef[j-1] = fmaf(-gw * c1, sc[j-1], coef[j-1]);
        coef[j]   = fmaf( gw * c2, sc[j],   coef[j]);
        wj *= (1.f / 0.9f);
    }
    float vi0 = 0.f, vi1 = 0.f;
#pragma unroll
    for (int n = 0; n < Nn; ++n) {
        vi0 = fmaf(coef[n], y0[n], vi0);
        vi1 = fmaf(coef[n], y1[n], vi1);
    }
    // z_last (per-lane) and its norm2
    const float z0l = y0[Nn-1] * sc[Nn-1], z1l = y1[Nn-1] * sc[Nn-1];
    const float x2l = zn2a[Nn-1];

    // --- v0t = projx(expmap0(logmap0(v_init) @ Wv + bv)) ---
    const float vin2 = wsum64(vi0 * vi0 + vi1 * vi1);
    const float vin  = fsqrtf_(fmaxf(vin2, EPSF * EPSF));
    const float lgv  = fatanh01(fminf(vin, MAXNF)) * frcp(vin);
    float* bc = bcu + c * Dd;
    *reinterpret_cast<float2*>(bc + 2 * lane) = make_float2(lgv * vi0, lgv * vi1);
    __syncthreads();

    float m0 = bv.x, m1 = bv.y;
    {
        const float4* bc4 = reinterpret_cast<const float4*>(bc);
#pragma unroll 4
        for (int k4 = 0; k4 < Dd / 4; ++k4) {
            const float4 t4 = bc4[k4];
            const float2 w0 = *reinterpret_cast<const float2*>(Wvp + (4*k4+0) * Dd);
            const float2 w1 = *reinterpret_cast<const float2*>(Wvp + (4*k4+1) * Dd);
            const float2 w2 = *reinterpret_cast<const float2*>(Wvp + (4*k4+2) * Dd);
            const float2 w3 = *reinterpret_cast<const float2*>(Wvp + (4*k4+3) * Dd);
            m0 = fmaf(t4.x, w0.x, m0); m1 = fmaf(t4.x, w0.y, m1);
            m0 = fmaf(t4.y, w1.x, m0); m1 = fmaf(t4.y, w1.y, m1);
            m0 = fmaf(t4.z, w2.x, m0); m1 = fmaf(t4.z, w2.y, m1);
            m0 = fmaf(t4.w, w3.x, m0); m1 = fmaf(t4.w, w3.y, m1);
        }
    }
    // batched: |m|^2 and z_last.m in one pipelined pair of butterflies
    float mn2 = m0 * m0 + m1 * m1;
    float zdm = z0l * m0 + z1l * m1;
#pragma unroll
    for (int off = 1; off < 64; off <<= 1) {
        mn2 += __shfl_xor(mn2, off, 64);
        zdm += __shfl_xor(zdm, off, 64);
    }
    const float mn  = fsqrtf_(fmaxf(mn2, EPSF * EPSF));
    const float th2 = ftanh_pos(mn);
    float sc2 = th2 * frcp(mn);
    float v0n = th2;
    if (v0n > MAXNF) { sc2 *= MAXNF * frcp(v0n); v0n = MAXNF; }
    const float v00 = m0 * sc2, v01 = m1 * sc2;
    const float v0n2 = mn2 * sc2 * sc2;
    const float zdotv = sc2 * zdm;

    const float lamx = 2.f * frcp(fmaxf(1.f - x2l, EPSF));
    const float sig  = frcp(1.f + __expf(-steps[c]));

#pragma unroll
    for (int t = 0; t < Tt; ++t) {
        const float alpha = sig * (float)(t + 1);
        const float vtn2  = alpha * alpha * v0n2;
        const float vtn   = fsqrtf_(fmaxf(vtn2, EPSF * EPSF));
        const float g     = ftanh_pos(0.5f * lamx * vtn);
        const float cyc   = g * alpha * frcp(vtn);     // y = cyc * v0t
        const float y2    = cyc * cyc * v0n2;
        const float xy    = cyc * zdotv;
        const float c1 = 1.f + 2.f * xy + y2;
        const float c2 = 1.f - x2l;
        const float rden = frcp(fmaxf(1.f + 2.f * xy + x2l * y2, EPSF));
        // analytic |r|^2
        float rn2 = rden * rden *
            (c1 * c1 * x2l + 2.f * c1 * c2 * xy + c2 * c2 * y2);
        float r0 = (c1 * z0l + c2 * cyc * v00) * rden;
        float r1 = (c1 * z1l + c2 * cyc * v01) * rden;
        float rn = fsqrtf_(fmaxf(rn2, EPSF * EPSF));
        if (rn > MAXNF) { const float s = MAXNF * frcp(rn); r0 *= s; r1 *= s; rn = MAXNF; }
        *reinterpret_cast<float2*>(&zfl[c][t][2 * lane]) = make_float2(r0, r1);
        if (lane == 0) zfns[c][t] = rn;
    }
    __syncthreads();

    // ======= Mobius fusion via Gram matrix: wave wid = horizon t =======
    {
        float mw0 = mobius_w[0], mw1 = mobius_w[1], mw2 = mobius_w[2], mw3 = mobius_w[3];
        const float mx = fmaxf(fmaxf(mw0, mw1), fmaxf(mw2, mw3));
        mw0 = __expf(mw0 - mx); mw1 = __expf(mw1 - mx);
        mw2 = __expf(mw2 - mx); mw3 = __expf(mw3 - mx);
        const float rse = frcp(mw0 + mw1 + mw2 + mw3);
        const float mwv[4] = {mw0 * rse, mw1 * rse, mw2 * rse, mw3 * rse};

        const int t = wid;
        float2 e[4];
#pragma unroll
        for (int i = 0; i < 4; ++i)
            e[i] = *reinterpret_cast<const float2*>(&zfl[i][t][2 * lane]);

        // 6 pairwise dots, batched butterfly
        float gp[6];
        gp[0] = e[0].x * e[1].x + e[0].y * e[1].y;   // G01
        gp[1] = e[0].x * e[2].x + e[0].y * e[2].y;   // G02
        gp[2] = e[0].x * e[3].x + e[0].y * e[3].y;   // G03
        gp[3] = e[1].x * e[2].x + e[1].y * e[2].y;   // G12
        gp[4] = e[1].x * e[3].x + e[1].y * e[3].y;   // G13
        gp[5] = e[2].x * e[3].x + e[2].y * e[3].y;   // G23
#pragma unroll
        for (int off = 1; off < 64; off <<= 1) {
#pragma unroll
            for (int k = 0; k < 6; ++k) gp[k] += __shfl_xor(gp[k], off, 64);
        }
        const float xn[4] = {zfns[0][t], zfns[1][t], zfns[2][t], zfns[3][t]};
        const float Gd[4] = {xn[0]*xn[0], xn[1]*xn[1], xn[2]*xn[2], xn[3]*xn[3]};
        // full symmetric Gram
        const float G[4][4] = {
            {Gd[0], gp[0], gp[1], gp[2]},
            {gp[0], Gd[1], gp[3], gp[4]},
            {gp[1], gp[3], Gd[2], gp[5]},
            {gp[2], gp[4], gp[5], Gd[3]}};
        // mob_smul scales
        float sm[4];
#pragma unroll
        for (int i = 0; i < 4; ++i)
            sm[i] = ftanh_pos(mwv[i] * fatanh01(xn[i])) * frcp(xn[i]);

        // scalar mobius chain on coefficients alpha
        float a0 = sm[0], a1 = 0.f, a2 = 0.f, a3 = 0.f;
        float cn2 = sm[0] * sm[0] * Gd[0];
#pragma unroll
        for (int i = 1; i < 4; ++i) {
            const float si = sm[i];
            const float xy = si * (a0 * G[0][i] + a1 * G[1][i] + a2 * G[2][i] + a3 * G[3][i]);
            const float y2 = si * si * Gd[i];
            const float c1 = 1.f + 2.f * xy + y2;
            const float c2 = 1.f - cn2;
            const float rden = frcp(fmaxf(1.f + 2.f * xy + cn2 * y2, EPSF));
            const float f1 = rden * c1, f2 = rden * c2 * si;
            a0 *= f1; a1 *= f1; a2 *= f1; a3 *= f1;
            if (i == 1) a1 += f2; else if (i == 2) a2 += f2; else a3 += f2;
            cn2 = rden * rden * (c1 * c1 * cn2 + 2.f * c1 * c2 * xy + c2 * c2 * y2);
        }
        float cn = fsqrtf_(fmaxf(cn2, EPSF * EPSF));
        float csc = 1.f;
        if (cn > MAXNF) { csc = MAXNF * frcp(cn); cn = MAXNF; }
        const float lg = fatanh01(cn) * frcp(cn) * csc;
        const float u0 = lg * (a0 * e[0].x + a1 * e[1].x + a2 * e[2].x + a3 * e[3].x);
        const float u1 = lg * (a0 * e[0].y + a1 * e[1].y + a2 * e[2].y + a3 * e[3].y);
        *reinterpret_cast<float2*>(&bcu[t * Dd + 2 * lane]) = make_float2(u0, u1);
    }

    // ---- hinge-loss partial (wave 0, parallel over 16 (comp,t) pairs) ----
    if (wid == 0) {
        float ddv = 0.f;
        if (lane < 16)
            ddv = 2.f * fatanh01(zfns[lane & 3][lane >> 2]);
        const float ddn = __shfl(ddv, lane + 1, 64);      // next comp, same t
        float hv = ((lane < 16) && ((lane & 3) != 3))
                 ? fmaxf(ddv - ddn + 0.1f, 0.f) : 0.f;
        hv = wsum64(hv);
        if (lane == 0) hpart[bf] = hv;
    }
    __syncthreads();

    // ---- reconstruction head, all 256 threads: h[t][j], j = tid ----
    {
        const float4* u4 = reinterpret_cast<const float4*>(bcu);
        float a0 = rec_b1[tid], a1 = a0, a2 = a0, a3 = a0;
        const float* w1p = rec_W1 + tid;
#pragma unroll 4
        for (int k4 = 0; k4 < Dd / 4; ++k4) {
            const float4 u0 = u4[0 * (Dd/4) + k4];
            const float4 u1 = u4[1 * (Dd/4) + k4];
            const float4 u2 = u4[2 * (Dd/4) + k4];
            const float4 u3 = u4[3 * (Dd/4) + k4];
            const float wa = w1p[(4*k4+0) * Hh];
            const float wb = w1p[(4*k4+1) * Hh];
            const float wc = w1p[(4*k4+2) * Hh];
            const float wd = w1p[(4*k4+3) * Hh];
            a0 = fmaf(u0.x, wa, a0); a0 = fmaf(u0.y, wb, a0);
            a0 = fmaf(u0.z, wc, a0); a0 = fmaf(u0.w, wd, a0);
            a1 = fmaf(u1.x, wa, a1); a1 = fmaf(u1.y, wb, a1);
            a1 = fmaf(u1.z, wc, a1); a1 = fmaf(u1.w, wd, a1);
            a2 = fmaf(u2.x, wa, a2); a2 = fmaf(u2.y, wb, a2);
            a2 = fmaf(u2.z, wc, a2); a2 = fmaf(u2.w, wd, a2);
            a3 = fmaf(u3.x, wa, a3); a3 = fmaf(u3.y, wb, a3);
            a3 = fmaf(u3.z, wc, a3); a3 = fmaf(u3.w, wd, a3);
        }
        xs[0 * Hh + tid] = fmaxf(a0, 0.f);
        xs[1 * Hh + tid] = fmaxf(a1, 0.f);
        xs[2 * Hh + tid] = fmaxf(a2, 0.f);
        xs[3 * Hh + tid] = fmaxf(a3, 0.f);
    }
    __syncthreads();

    // ---- seg outputs: 96 of them, threads 0..95 ----
    if (tid < Tt * SEGc) {
        const int t = tid / SEGc, s = tid - t * SEGc;
        const float4* h4 = reinterpret_cast<const float4*>(xs + t * Hh);
        const float* w2p = rec_W2 + s;
        float acc = rec_b2[s];
#pragma unroll 4
        for (int j4 = 0; j4 < Hh / 4; ++j4) {
            const float4 h = h4[j4];
            acc = fmaf(h.x, w2p[(4*j4+0) * SEGc], acc);
            acc = fmaf(h.y, w2p[(4*j4+1) * SEGc], acc);
            acc = fmaf(h.z, w2p[(4*j4+2) * SEGc], acc);
            acc = fmaf(h.w, w2p[(4*j4+3) * SEGc], acc);
        }
        const float val = (acc - rb) * frcp(rw) * stdv + mean;   // RevIN denorm
        out[(b * (Tt * SEGc) + tid) * Ff + f] = val;
    }
}

// ---------------- deterministic hloss reduction ----------------
__global__ __launch_bounds__(256) void hloss_kernel(
    const float* __restrict__ hpart, float* __restrict__ out)
{
    __shared__ float sm[256];
    const int tid = threadIdx.x;
    float s = 0.f;
    for (int i = tid; i < BFc; i += 256) s += hpart[i];
    sm[tid] = s;
    __syncthreads();
    for (int off = 128; off > 0; off >>= 1) {
        if (tid < off) sm[tid] += sm[tid + off];
        __syncthreads();
    }
    if (tid == 0) out[Bb * Tt * SEGc * Ff] = sm[0] / (float)(BFc * Tt);
}

extern "C" void kernel_launch(void* const* d_in, const int* in_sizes, int n_in,
                              void* d_out, int out_size, void* d_ws, size_t ws_size,
                              hipStream_t stream) {
    const float* trend   = (const float*)d_in[0];
    const float* scoarse = (const float*)d_in[1];
    const float* sfine   = (const float*)d_in[2];
    const float* resid   = (const float*)d_in[3];
    const float* revin_w = (const float*)d_in[4];
    const float* revin_b = (const float*)d_in[5];
    const float* enc_W   = (const float*)d_in[6];
    const float* enc_b   = (const float*)d_in[7];
    const float* vel_W   = (const float*)d_in[8];
    const float* vel_b   = (const float*)d_in[9];
    const float* steps   = (const float*)d_in[10];
    const float* mobw    = (const float*)d_in[11];
    const float* rec_W1  = (const float*)d_in[12];
    const float* rec_b1  = (const float*)d_in[13];
    const float* rec_W2  = (const float*)d_in[14];
    const float* rec_b2  = (const float*)d_in[15];

    float* out = (float*)d_out;
    float* wsf = (float*)d_ws;           // hpart[8192]

    fused_kernel<<<BFc, 256, 0, stream>>>(
        trend, scoarse, sfine, resid, revin_w, revin_b,
        enc_W, enc_b, vel_W, vel_b, steps, mobw,
        rec_W1, rec_b1, rec_W2, rec_b2,
        out, wsf);
    hloss_kernel<<<1, 256, 0, stream>>>(wsf, out);
}